// Round 3
// baseline (2999.510 us; speedup 1.0000x reference)
//
#include <hip/hip_runtime.h>

typedef unsigned int u32;
typedef unsigned short u16;

typedef short short8 __attribute__((ext_vector_type(8)));
typedef float f32x4 __attribute__((ext_vector_type(4)));

// ---------------- numeric helpers ----------------

__device__ __forceinline__ float fast_exp2(float x) {
#if __has_builtin(__builtin_amdgcn_exp2f)
  return __builtin_amdgcn_exp2f(x);
#else
  return exp2f(x);
#endif
}
__device__ __forceinline__ float fast_rcp(float x) {
#if __has_builtin(__builtin_amdgcn_rcpf)
  return __builtin_amdgcn_rcpf(x);
#else
  return 1.0f / x;
#endif
}
__device__ __forceinline__ float sigmf_(float x) {
  return fast_rcp(1.0f + fast_exp2(-1.44269504088896f * x));
}
__device__ __forceinline__ float tanhf_(float x) {
  float e = fast_exp2(2.88539008177793f * x);  // exp(2x)
  return 1.0f - 2.0f * fast_rcp(e + 1.0f);
}
__device__ __forceinline__ u16 f2bf(float x) {
  u32 u = __float_as_uint(x);
  u32 r = (u + 0x7fffu + ((u >> 16) & 1u)) >> 16;
  return (u16)r;
}

// ---------------- threefry2x32 (JAX-exact) ----------------

__device__ __forceinline__ void tf_round(u32& x0, u32& x1, int r) {
  x0 += x1;
  x1 = (x1 << r) | (x1 >> (32 - r));
  x1 ^= x0;
}
__device__ void threefry(u32 k0, u32 k1, u32 c0, u32 c1, u32& o0, u32& o1) {
  u32 k2 = k0 ^ k1 ^ 0x1BD11BDAu;
  u32 x0 = c0 + k0, x1 = c1 + k1;
  tf_round(x0, x1, 13); tf_round(x0, x1, 15); tf_round(x0, x1, 26); tf_round(x0, x1, 6);
  x0 += k1; x1 += k2 + 1u;
  tf_round(x0, x1, 17); tf_round(x0, x1, 29); tf_round(x0, x1, 16); tf_round(x0, x1, 24);
  x0 += k2; x1 += k0 + 2u;
  tf_round(x0, x1, 13); tf_round(x0, x1, 15); tf_round(x0, x1, 26); tf_round(x0, x1, 6);
  x0 += k0; x1 += k1 + 3u;
  tf_round(x0, x1, 17); tf_round(x0, x1, 29); tf_round(x0, x1, 16); tf_round(x0, x1, 24);
  x0 += k1; x1 += k2 + 4u;
  tf_round(x0, x1, 13); tf_round(x0, x1, 15); tf_round(x0, x1, 26); tf_round(x0, x1, 6);
  x0 += k2; x1 += k0 + 5u;
  o0 = x0; o1 = x1;
}

#define JAX_PARTITIONABLE 1

// masks layout: [layer(2)][type(3: out,h,c)][b*256+h (16384)]
__global__ void masks_kernel(float* __restrict__ masks) {
  int gid = blockIdx.x * 256 + threadIdx.x;
  if (gid >= 2 * 3 * 16384) return;
  int l = gid / 49152;
  int rem = gid - l * 49152;
  int typ = rem / 16384;
  int i = rem - typ * 16384;
  u32 bits;
#if JAX_PARTITIONABLE
  u32 lk0, lk1, mk0, mk1, y0, y1;
  threefry(0u, 42u, 0u, (u32)l, lk0, lk1);      // split(MASK_KEY,2)[l]
  threefry(lk0, lk1, 0u, (u32)typ, mk0, mk1);   // split(layer_key,3)[typ]
  threefry(mk0, mk1, 0u, (u32)i, y0, y1);       // random_bits, counter = linear idx
  bits = y0 ^ y1;
#else
  u32 a0, a1, b0, b1;
  threefry(0u, 42u, 0u, 2u, a0, a1);
  threefry(0u, 42u, 1u, 3u, b0, b1);
  u32 lk0 = (l == 0) ? a0 : a1;
  u32 lk1 = (l == 0) ? b0 : b1;
  u32 e00, e01, e10, e11, e20, e21;
  threefry(lk0, lk1, 0u, 3u, e00, e01);
  threefry(lk0, lk1, 1u, 4u, e10, e11);
  threefry(lk0, lk1, 2u, 5u, e20, e21);
  u32 mk0 = (typ == 0) ? e00 : (typ == 1) ? e20 : e11;
  u32 mk1 = (typ == 0) ? e10 : (typ == 1) ? e01 : e21;
  u32 p = (i < 8192) ? (u32)i : (u32)(i - 8192);
  u32 y0, y1;
  threefry(mk0, mk1, p, p + 8192u, y0, y1);
  bits = (i < 8192) ? y0 : y1;
#endif
  float u = __uint_as_float((bits >> 9) | 0x3f800000u) - 1.0f;
  masks[gid] = (u < 0.75f) ? (1.0f / 0.75f) : 0.0f;
}

// ---------------- prep kernels ----------------

__global__ void conv_bf16(const float* __restrict__ src, u16* __restrict__ dst, int n) {
  int gid = blockIdx.x * 256 + threadIdx.x;
  if (gid < n) dst[gid] = f2bf(src[gid]);
}

// Pack W_hh [1024][256] f32 into MFMA A-fragment layout:
// Wf[((w*128 + f)*64 + l)*8 + j] = bf16 of W[w*256 + rb*16 + (l&15)][kc*32 + (l>>4)*8 + j]
// where f = rb*8 + kc  (rb 0..15, kc 0..7), w = wave 0..3, l = lane 0..63.
__global__ void pack_wf(const float* __restrict__ W, u16* __restrict__ Wf) {
  int gid = blockIdx.x * 256 + threadIdx.x;  // 262144
  int j = gid & 7;
  int l = (gid >> 3) & 63;
  int f = (gid >> 9) & 127;
  int w = gid >> 16;
  int rb = f >> 3, kc = f & 7;
  int row = w * 256 + rb * 16 + (l & 15);
  int col = kc * 32 + (l >> 4) * 8 + j;
  Wf[gid] = f2bf(W[row * 256 + col]);
}

__global__ void add_bias(const float* __restrict__ a, const float* __restrict__ b,
                         float* __restrict__ o, int n) {
  int gid = blockIdx.x * 256 + threadIdx.x;
  if (gid < n) o[gid] = a[gid] + b[gid];
}

// ---------------- input-projection GEMM (bf16 MFMA) ----------------
// C[m][n] = sum_k A[m][k] * Bw[n][k];  A [32768][256] bf16, Bw [1024][256] bf16
// output scattered into xg[t][b][n] with m = b*512 + t
__global__ __launch_bounds__(256) void gemm_xg(const u16* __restrict__ A,
                                               const u16* __restrict__ Bw,
                                               float* __restrict__ xg) {
  __shared__ uint4 Als[2048];  // [kb 0..31][m 0..63], 16B units (8 bf16 along k)
  __shared__ uint4 Bls[2048];
  int tid = threadIdx.x;
  int m0 = blockIdx.x * 64;
  int n0 = blockIdx.y * 64;
  {
    int row = tid >> 2, kseg = tid & 3;
    const uint4* Ag = (const uint4*)(A + (size_t)(m0 + row) * 256);
    const uint4* Bg = (const uint4*)(Bw + (size_t)(n0 + row) * 256);
#pragma unroll
    for (int uu = 0; uu < 8; ++uu) {
      int kb = kseg * 8 + uu;
      Als[kb * 64 + row] = Ag[kb];
      Bls[kb * 64 + row] = Bg[kb];
    }
  }
  __syncthreads();
  int w = tid >> 6, l = tid & 63;
  int wm = (w >> 1) * 32, wn = (w & 1) * 32;
  int lm = l & 15, q = l >> 4;
  f32x4 acc00 = {0.f, 0.f, 0.f, 0.f}, acc01 = acc00, acc10 = acc00, acc11 = acc00;
#pragma unroll
  for (int ks = 0; ks < 8; ++ks) {
    int kb = ks * 4 + q;
    short8 a0 = __builtin_bit_cast(short8, Als[kb * 64 + wm + lm]);
    short8 a1 = __builtin_bit_cast(short8, Als[kb * 64 + wm + 16 + lm]);
    short8 b0 = __builtin_bit_cast(short8, Bls[kb * 64 + wn + lm]);
    short8 b1 = __builtin_bit_cast(short8, Bls[kb * 64 + wn + 16 + lm]);
    acc00 = __builtin_amdgcn_mfma_f32_16x16x32_bf16(a0, b0, acc00, 0, 0, 0);
    acc01 = __builtin_amdgcn_mfma_f32_16x16x32_bf16(a0, b1, acc01, 0, 0, 0);
    acc10 = __builtin_amdgcn_mfma_f32_16x16x32_bf16(a1, b0, acc10, 0, 0, 0);
    acc11 = __builtin_amdgcn_mfma_f32_16x16x32_bf16(a1, b1, acc11, 0, 0, 0);
  }
#pragma unroll
  for (int fm = 0; fm < 2; ++fm)
#pragma unroll
    for (int fn = 0; fn < 2; ++fn) {
      f32x4 acc = (fm == 0) ? ((fn == 0) ? acc00 : acc01) : ((fn == 0) ? acc10 : acc11);
#pragma unroll
      for (int r = 0; r < 4; ++r) {
        int m = m0 + wm + fm * 16 + q * 4 + r;  // C/D row = quad*4 + reg
        int n = n0 + wn + fn * 16 + lm;         // C/D col = lane&15
        int bb = m >> 9, tt = m & 511;
        xg[(size_t)tt * 65536 + (size_t)bb * 1024 + n] = acc[r];
      }
    }
}

// ---------------- persistent MFMA recurrence ----------------
// One 256-thread block (4 waves) per batch element. Wave w owns gate rows
// [w*256, w*256+256) as 16 row-blocks x 8 k-chunks of mfma_16x16x32 A-frags.
// Frag storage split: 64 frags -> AGPR (compiler pressure), 28 -> VGPR,
// 36 -> LDS (re-read each step; DS pipe overlaps MFMA pipe).
// B operand = h broadcast into all 16 cols => every lane's D is valid; lane
// (q,c) scatters chain rb==c to gates via one exec-masked ds_write_b128.
#define NW 4
#define F_AGPR 64
#define F_VGPR 28
#define F_REG  (F_AGPR + F_VGPR)  // 92
#define F_LDS  36                 // frags 92..127

__global__ __launch_bounds__(256) void lstm_rec(
    const short8* __restrict__ Wf,   // [4][128][64] frags
    const float* __restrict__ xg,    // [512][64][1024]
    const float* __restrict__ bias,  // [1024] (b_ih + b_hh)
    const float* __restrict__ masks, // [3][16384] this layer (out,h,c)
    float* __restrict__ outF,        // layer2: d_out [64][512][256], else null
    u16* __restrict__ outB)          // layer1: bf16 out for next GEMM, else null
{
  __shared__ short8 Wlds[NW * F_LDS * 64];   // 147456 B
  __shared__ alignas(16) float gates[1024];  // 4096 B
  __shared__ alignas(16) u16 hbf[256];       // 512 B

  const int tid = threadIdx.x;
  const int w = tid >> 6, l = tid & 63;
  const int b = blockIdx.x;
  const int q = l >> 4;

  // ---- load weight fragments ----
  const short8* Wfw = Wf + (size_t)w * 128 * 64 + l;
  short8 fa[F_AGPR];
  short8 fv[F_VGPR];
#pragma unroll
  for (int f = 0; f < F_AGPR; ++f) fa[f] = Wfw[(size_t)f * 64];
#pragma unroll
  for (int f = 0; f < F_VGPR; ++f) fv[f] = Wfw[(size_t)(F_AGPR + f) * 64];
#pragma unroll
  for (int f = 0; f < F_LDS; ++f)
    Wlds[(w * F_LDS + f) * 64 + l] = Wfw[(size_t)(F_REG + f) * 64];

  hbf[tid] = 0;

  const float bias0 = bias[tid];
  const float bias1 = bias[tid + 256];
  const float bias2 = bias[tid + 512];
  const float bias3 = bias[tid + 768];
  const float m_out = masks[b * 256 + tid];
  const float m_h   = masks[16384 + b * 256 + tid];
  const float m_c   = masks[32768 + b * 256 + tid];
  float c = 0.f;

  const float* xgb = xg + b * 1024;
  float* outFb = outF ? outF + (size_t)b * 512 * 256 : (float*)0;
  u16* outBb = outB ? outB + (size_t)b * 512 * 256 : (u16*)0;

  float xgc0 = xgb[tid];
  float xgc1 = xgb[tid + 256];
  float xgc2 = xgb[tid + 512];
  float xgc3 = xgb[tid + 768];

  __syncthreads();

  for (int t = 0; t < 512; ++t) {
    // prefetch next step's xg (HBM latency hides under this step's compute)
    float xgn0 = 0.f, xgn1 = 0.f, xgn2 = 0.f, xgn3 = 0.f;
    if (t < 511) {
      const float* xn = xgb + (size_t)(t + 1) * 65536;
      xgn0 = xn[tid];
      xgn1 = xn[tid + 256];
      xgn2 = xn[tid + 512];
      xgn3 = xn[tid + 768];
    }

    // B-frags: h broadcast into all 16 cols. lane needs h[kc*32 + q*8 + j].
    short8 bf[8];
    const short8* hv = (const short8*)hbf;
#pragma unroll
    for (int kc = 0; kc < 8; ++kc) bf[kc] = hv[kc * 4 + q];

    f32x4 acc[16];
#pragma unroll
    for (int rb = 0; rb < 16; ++rb) acc[rb] = f32x4{0.f, 0.f, 0.f, 0.f};

    // kc-outer / rb-inner: 16 independent MFMA chains stay in flight
#pragma unroll
    for (int kc = 0; kc < 8; ++kc) {
#pragma unroll
      for (int rb = 0; rb < 16; ++rb) {
        const int f = rb * 8 + kc;
        short8 af;
        if (f < F_AGPR) af = fa[f];
        else if (f < F_REG) af = fv[f - F_AGPR];
        else af = Wlds[(w * F_LDS + (f - F_REG)) * 64 + l];
        acc[rb] = __builtin_amdgcn_mfma_f32_16x16x32_bf16(af, bf[kc], acc[rb], 0, 0, 0);
      }
    }

    // scatter: lane (q,c) writes chain rb==c rows [rb*16+q*4, +4)
    const int cidx = l & 15;
#pragma unroll
    for (int rb = 0; rb < 16; ++rb) {
      if (cidx == rb)
        *(f32x4*)&gates[w * 256 + rb * 16 + q * 4] = acc[rb];
    }
    __syncthreads();

    // gate phase: all 256 threads, one h each
    {
      float gi = gates[tid] + xgc0 + bias0;
      float gf = gates[tid + 256] + xgc1 + bias1;
      float gg = gates[tid + 512] + xgc2 + bias2;
      float go = gates[tid + 768] + xgc3 + bias3;
      float fi = sigmf_(gi), ff = sigmf_(gf), fo = sigmf_(go);
      float tg = tanhf_(gg);
      c = ff * c + fi * tg;
      float hn = fo * tanhf_(c);
      float ov = hn * m_out;
      if (outFb) outFb[t * 256 + tid] = ov;
      if (outBb) outBb[t * 256 + tid] = f2bf(ov);
      hbf[tid] = f2bf(hn * m_h);  // variational h-mask applied to carry
      c *= m_c;                   // c-mask applied to carry
    }
    __syncthreads();

    xgc0 = xgn0; xgc1 = xgn1; xgc2 = xgn2; xgc3 = xgn3;
  }
}

// ---------------- launch ----------------

extern "C" void kernel_launch(void* const* d_in, const int* in_sizes, int n_in,
                              void* d_out, int out_size, void* d_ws, size_t ws_size,
                              hipStream_t stream) {
  const float* x    = (const float*)d_in[0];
  const float* Wih0 = (const float*)d_in[1];
  const float* Whh0 = (const float*)d_in[2];
  const float* bih0 = (const float*)d_in[3];
  const float* bhh0 = (const float*)d_in[4];
  const float* Wih1 = (const float*)d_in[5];
  const float* Whh1 = (const float*)d_in[6];
  const float* bih1 = (const float*)d_in[7];
  const float* bhh1 = (const float*)d_in[8];
  float* out = (float*)d_out;

  char* w = (char*)d_ws;
  float* masks = (float*)(w + 0);             // 393216 B
  float* biasb = (float*)(w + 393216);        // 8192 B
  u16* Wf0     = (u16*)(w + 401408);          // 524288 B
  u16* Wf1     = (u16*)(w + 925696);          // 524288 B
  u16* Wih0b   = (u16*)(w + 1449984);         // 524288 B
  u16* Wih1b   = (u16*)(w + 1974272);         // 524288 B
  u16* xb      = (u16*)(w + 2498560);         // 16777216 B
  u16* o1b     = (u16*)(w + 19275776);        // 16777216 B
  float* xg    = (float*)(w + 36052992);      // 134217728 B (total ~170.3 MB)

  hipLaunchKernelGGL(masks_kernel, dim3(384), dim3(256), 0, stream, masks);
  hipLaunchKernelGGL(conv_bf16, dim3(32768), dim3(256), 0, stream, x, xb, 8388608);
  hipLaunchKernelGGL(conv_bf16, dim3(1024), dim3(256), 0, stream, Wih0, Wih0b, 262144);
  hipLaunchKernelGGL(conv_bf16, dim3(1024), dim3(256), 0, stream, Wih1, Wih1b, 262144);
  hipLaunchKernelGGL(pack_wf, dim3(1024), dim3(256), 0, stream, Whh0, Wf0);
  hipLaunchKernelGGL(pack_wf, dim3(1024), dim3(256), 0, stream, Whh1, Wf1);
  hipLaunchKernelGGL(add_bias, dim3(4), dim3(256), 0, stream, bih0, bhh0, biasb, 1024);
  hipLaunchKernelGGL(add_bias, dim3(4), dim3(256), 0, stream, bih1, bhh1, biasb + 1024, 1024);

  // layer 1
  hipLaunchKernelGGL(gemm_xg, dim3(512, 16), dim3(256), 0, stream, xb, Wih0b, xg);
  hipLaunchKernelGGL(lstm_rec, dim3(64), dim3(256), 0, stream, (const short8*)Wf0, xg,
                     biasb, masks, (float*)nullptr, o1b);
  // layer 2
  hipLaunchKernelGGL(gemm_xg, dim3(512, 16), dim3(256), 0, stream, o1b, Wih1b, xg);
  hipLaunchKernelGGL(lstm_rec, dim3(64), dim3(256), 0, stream, (const short8*)Wf1, xg,
                     biasb + 1024, masks + 49152, out, (u16*)nullptr);
}